// Round 2
// baseline (353.583 us; speedup 1.0000x reference)
//
#include <hip/hip_runtime.h>
#include <hip/hip_bf16.h>
#include <stdint.h>

// Problem constants
#define AN 64
#define HN 1024
#define BN 512
#define GAUSS_CONST (-3.989422804014327f)   // V0 / (sqrt(2*pi)*sigma0)
#define INV_2SIG2 2.0f

typedef __attribute__((ext_vector_type(8))) short short8;
typedef __attribute__((ext_vector_type(4))) float floatx4;

__device__ inline unsigned short f2bf(float f) {
  __hip_bfloat16 h = __float2bfloat16(f);        // RNE
  return *reinterpret_cast<unsigned short*>(&h);
}

__device__ inline void gload_lds16(const void* g, void* l) {
  __builtin_amdgcn_global_load_lds(
      (const __attribute__((address_space(1))) void*)g,
      (__attribute__((address_space(3))) void*)l, 16, 0, 0);
}

// ---------------------------------------------------------------------------
// prep: W2T bf16, W2 bf16, W1T f32, c_j = sum_a W1[a,j]^2
__global__ __launch_bounds__(256) void k_prep(
    const float* __restrict__ W1, const float* __restrict__ W2,
    unsigned short* __restrict__ W2T, unsigned short* __restrict__ W2bf,
    float* __restrict__ W1T, float* __restrict__ c) {
  int idx = blockIdx.x * 256 + threadIdx.x;   // exactly 1M threads
  float v = W2[idx];
  W2bf[idx] = f2bf(v);
  int j = idx >> 10, k = idx & 1023;
  W2T[k * HN + j] = f2bf(v);
  if (idx < AN * HN) {
    int a = idx >> 10, jj = idx & 1023;
    W1T[jj * AN + a] = W1[idx];
  }
  if (idx < HN) {
    float s = 0.f;
    for (int a = 0; a < AN; ++a) { float x = W1[a * HN + idx]; s += x * x; }
    c[idx] = s;
  }
}

// ---------------------------------------------------------------------------
// layer 1 forward + pot + gint.  1 block = 1 sample.
__global__ __launch_bounds__(256) void k_fwd1(
    const float* __restrict__ x, const float* __restrict__ W1,
    const float* __restrict__ b1, const float* __restrict__ c,
    unsigned short* __restrict__ h1bf, float* __restrict__ t1f,
    float* __restrict__ a1, float* __restrict__ potgint) {
  __shared__ float xs[AN];
  __shared__ float red[4];
  int s = blockIdx.x, tid = threadIdx.x;
  if (tid < AN) xs[tid] = x[s * AN + tid];
  __syncthreads();
  #pragma unroll
  for (int cc = 0; cc < 4; ++cc) {
    int j = tid + cc * 256;
    float z = b1[j];
    #pragma unroll 8
    for (int a = 0; a < AN; ++a) z += xs[a] * W1[a * HN + j];
    float h = tanhf(z), t = 1.f - h * h;
    h1bf[s * HN + j] = f2bf(h);
    t1f[s * HN + j] = t;
    a1[s * HN + j] = c[j] * h * t;
  }
  // pot + gint
  float val = 0.f;
  #pragma unroll
  for (int p = 0; p < 16; ++p) {
    int idx = tid + p * 256;
    int i = idx >> 6, jj = idx & 63;
    if (jj > i) { float d = xs[i] - xs[jj]; val += __expf(-INV_2SIG2 * d * d); }
  }
  val *= GAUSS_CONST;
  if (tid < AN) val += 0.5f * xs[tid] * xs[tid];
  #pragma unroll
  for (int o = 32; o > 0; o >>= 1) val += __shfl_down(val, o, 64);
  if ((tid & 63) == 0) red[tid >> 6] = val;
  __syncthreads();
  if (tid == 0) potgint[s] = red[0] + red[1] + red[2] + red[3];
}

// ---------------------------------------------------------------------------
// z2 = h1 @ W2 + b2 -> dcoef = -2 h2 t2 W3, v = t2*W3 (bf16)
// block tile 16 samples x 64 cols, split-K over 4 waves.
__global__ __launch_bounds__(256) void k_z2(
    const unsigned short* __restrict__ h1bf, const unsigned short* __restrict__ W2T,
    const float* __restrict__ b2, const float* __restrict__ W3,
    float* __restrict__ dcoef, unsigned short* __restrict__ vbf) {
  __shared__ float redL[4 * 16 * 64];
  int n0 = blockIdx.x * 64, m0 = blockIdx.y * 16;
  int tid = threadIdx.x, w = tid >> 6, l = tid & 63, lr = l & 15, kg = l >> 4;
  floatx4 acc[4];
  #pragma unroll
  for (int nf = 0; nf < 4; ++nf) acc[nf] = (floatx4){0.f, 0.f, 0.f, 0.f};
  int arow = m0 + lr;
  for (int kt = 0; kt < 8; ++kt) {
    int kb = w * 256 + kt * 32 + kg * 8;
    short8 af = *reinterpret_cast<const short8*>(&h1bf[arow * HN + kb]);
    #pragma unroll
    for (int nf = 0; nf < 4; ++nf) {
      short8 bf_ = *reinterpret_cast<const short8*>(&W2T[(n0 + nf * 16 + lr) * HN + kb]);
      acc[nf] = __builtin_amdgcn_mfma_f32_16x16x32_bf16(af, bf_, acc[nf], 0, 0, 0);
    }
  }
  #pragma unroll
  for (int nf = 0; nf < 4; ++nf)
    #pragma unroll
    for (int r = 0; r < 4; ++r)
      redL[w * 1024 + (kg * 4 + r) * 64 + nf * 16 + lr] = acc[nf][r];
  __syncthreads();
  #pragma unroll
  for (int t = 0; t < 4; ++t) {
    int e = tid + t * 256;
    float z = redL[e] + redL[1024 + e] + redL[2048 + e] + redL[3072 + e];
    int row = e >> 6, col = e & 63;
    int s = m0 + row, k2 = n0 + col;
    z += b2[k2];
    float h = tanhf(z), tt = 1.f - h * h, w3 = W3[k2];
    dcoef[s * HN + k2] = -2.f * h * tt * w3;
    vbf[s * HN + k2] = f2bf(tt * w3);
  }
}

// ---------------------------------------------------------------------------
// w = v @ W2^T  (w[s,j] = sum_k v[s,k] W2[j,k]) -> store f32
__global__ __launch_bounds__(256) void k_w(
    const unsigned short* __restrict__ vbf, const unsigned short* __restrict__ W2bf,
    float* __restrict__ wbuf) {
  __shared__ float redL[4 * 16 * 64];
  int n0 = blockIdx.x * 64, m0 = blockIdx.y * 16;
  int tid = threadIdx.x, w = tid >> 6, l = tid & 63, lr = l & 15, kg = l >> 4;
  floatx4 acc[4];
  #pragma unroll
  for (int nf = 0; nf < 4; ++nf) acc[nf] = (floatx4){0.f, 0.f, 0.f, 0.f};
  int arow = m0 + lr;
  for (int kt = 0; kt < 8; ++kt) {
    int kb = w * 256 + kt * 32 + kg * 8;
    short8 af = *reinterpret_cast<const short8*>(&vbf[arow * HN + kb]);
    #pragma unroll
    for (int nf = 0; nf < 4; ++nf) {
      short8 bf_ = *reinterpret_cast<const short8*>(&W2bf[(n0 + nf * 16 + lr) * HN + kb]);
      acc[nf] = __builtin_amdgcn_mfma_f32_16x16x32_bf16(af, bf_, acc[nf], 0, 0, 0);
    }
  }
  #pragma unroll
  for (int nf = 0; nf < 4; ++nf)
    #pragma unroll
    for (int r = 0; r < 4; ++r)
      redL[w * 1024 + (kg * 4 + r) * 64 + nf * 16 + lr] = acc[nf][r];
  __syncthreads();
  #pragma unroll
  for (int t = 0; t < 4; ++t) {
    int e = tid + t * 256;
    float z = redL[e] + redL[1024 + e] + redL[2048 + e] + redL[3072 + e];
    int row = e >> 6, col = e & 63;
    wbuf[(m0 + row) * HN + (n0 + col)] = z;
  }
}

// ---------------------------------------------------------------------------
// BIG: q[s,k] = sum_a M[a,k]^2,  M = (W1 .* t1[s]) @ W2   (K=1024 in-block)
// 128x128 tile (2 samples x 128 cols), BK=64.
// Single-buffered (m97 2-barrier loop, 32 KB LDS -> 4-5 blocks/CU) with
// 16B-slot XOR swizzle (T2): phys_slot = logical_slot ^ (row & 7).
// B is filled via global_load_lds (linear dest) -> pre-swizzle the GLOBAL
// source address (rule #21); A is reg-packed -> swizzle the ds_write addr.
__global__ __launch_bounds__(256) void k_big(
    const float* __restrict__ W1, const float* __restrict__ t1f,
    const unsigned short* __restrict__ W2T, float* __restrict__ q) {
  __shared__ unsigned short Ab[128 * 64];   // [row(2 samples x 64a)][j] swizzled
  __shared__ unsigned short Bb[128 * 64];   // [col][j] swizzled
  int n0 = blockIdx.x * 128;
  int s0 = blockIdx.y * 2;
  int tid = threadIdx.x, w = tid >> 6, l = tid & 63;
  int lr = l & 15, kg = l >> 4;
  int rh = w >> 1, ch = w & 1;                 // wave: 64-row half (sample), 64-col half

  // A staging geometry: thread covers row ar, 32 j's (4 chunks of 8)
  int ar = tid >> 1;
  int ajh = (tid & 1) * 32;
  int sA = s0 + (ar >> 6);
  int aa = ar & 63;
  int arSw = (ar & 7) * 8;                     // A write swizzle (elements)

  // B staging: lane tid fills linear LDS slot (row = tid>>3, slot = tid&7);
  // that phys slot holds logical slot (tid&7)^(row&7) -> fetch that j from global.
  int bRow = tid >> 3;
  int bJsw = ((tid & 7) ^ ((tid >> 3) & 7)) * 8;

  auto stage = [&](int kt) {
    int j0 = kt * 64;
    // B via async global->LDS first (VMEM in flight while we pack A)
    #pragma unroll
    for (int p = 0; p < 4; ++p) {
      gload_lds16(&W2T[(n0 + p * 32 + bRow) * HN + j0 + bJsw], &Bb[p * 2048 + tid * 8]);
    }
    // A-operand global loads (f32 W1 + f32 t1)
    floatx4 wv[8], tv[8];
    #pragma unroll
    for (int cc = 0; cc < 4; ++cc) {
      int j = ajh + cc * 8;
      const floatx4* wp = reinterpret_cast<const floatx4*>(&W1[aa * HN + j0 + j]);
      const floatx4* tp = reinterpret_cast<const floatx4*>(&t1f[sA * HN + j0 + j]);
      wv[cc * 2] = wp[0]; wv[cc * 2 + 1] = wp[1];
      tv[cc * 2] = tp[0]; tv[cc * 2 + 1] = tp[1];
    }
    // pack P = W1*t1 -> bf16, write to LDS at swizzled slot
    #pragma unroll
    for (int cc = 0; cc < 4; ++cc) {
      int j = ajh + cc * 8;
      short8 out;
      #pragma unroll
      for (int e = 0; e < 4; ++e) out[e] = (short)f2bf(wv[cc * 2][e] * tv[cc * 2][e]);
      #pragma unroll
      for (int e = 0; e < 4; ++e) out[4 + e] = (short)f2bf(wv[cc * 2 + 1][e] * tv[cc * 2 + 1][e]);
      *reinterpret_cast<short8*>(&Ab[ar * 64 + (j ^ arSw)]) = out;
    }
  };

  floatx4 acc[4][4];
  #pragma unroll
  for (int mf = 0; mf < 4; ++mf)
    #pragma unroll
    for (int nf = 0; nf < 4; ++nf) acc[mf][nf] = (floatx4){0.f, 0.f, 0.f, 0.f};

  int aSw = (lr & 7) * 8;                       // read swizzle: row&7 == lr&7
  for (int kt = 0; kt < 16; ++kt) {
    stage(kt);
    __syncthreads();
    #pragma unroll
    for (int ks = 0; ks < 2; ++ks) {
      int kb = ks * 32 + kg * 8;
      int kbSw = kb ^ aSw;
      short8 afr[4], bfr[4];
      #pragma unroll
      for (int mf = 0; mf < 4; ++mf)
        afr[mf] = *reinterpret_cast<const short8*>(&Ab[(rh * 64 + mf * 16 + lr) * 64 + kbSw]);
      #pragma unroll
      for (int nf = 0; nf < 4; ++nf)
        bfr[nf] = *reinterpret_cast<const short8*>(&Bb[(ch * 64 + nf * 16 + lr) * 64 + kbSw]);
      #pragma unroll
      for (int mf = 0; mf < 4; ++mf)
        #pragma unroll
        for (int nf = 0; nf < 4; ++nf)
          acc[mf][nf] = __builtin_amdgcn_mfma_f32_16x16x32_bf16(afr[mf], bfr[nf], acc[mf][nf], 0, 0, 0);
    }
    __syncthreads();
  }

  // epilogue: q[s, col] = sum over 64 rows of M^2
  int sOut = s0 + rh;
  #pragma unroll
  for (int nf = 0; nf < 4; ++nf) {
    float v = 0.f;
    #pragma unroll
    for (int mf = 0; mf < 4; ++mf)
      #pragma unroll
      for (int r = 0; r < 4; ++r) v += acc[mf][nf][r] * acc[mf][nf][r];
    v += __shfl_xor(v, 16, 64);
    v += __shfl_xor(v, 32, 64);
    if (l < 16) q[sOut * HN + n0 + ch * 64 + nf * 16 + l] = v;
  }
}

// ---------------------------------------------------------------------------
// finale: per sample combine T1, T2, sum g^2, pot+gint
__global__ __launch_bounds__(256) void k_fin(
    const float* __restrict__ wbuf, const float* __restrict__ a1,
    const float* __restrict__ dcoef, const float* __restrict__ q,
    const float* __restrict__ t1f, const float* __restrict__ W1T,
    const float* __restrict__ potgint, float* __restrict__ out) {
  __shared__ float s_lds[HN];
  __shared__ float gl[256];
  __shared__ float red1[4], red2[4];
  int s = blockIdx.x, tid = threadIdx.x;
  float p1 = 0.f, p2 = 0.f;
  #pragma unroll
  for (int cc = 0; cc < 4; ++cc) {
    int j = tid + cc * 256;
    float wv = wbuf[s * HN + j];
    p1 += a1[s * HN + j] * wv;
    p2 += dcoef[s * HN + j] * q[s * HN + j];
    s_lds[j] = t1f[s * HN + j] * wv;
  }
  __syncthreads();
  int part = tid >> 6, a = tid & 63;
  float gp = 0.f;
  for (int jj = part * 256; jj < part * 256 + 256; ++jj)
    gp += s_lds[jj] * W1T[jj * AN + a];
  gl[tid] = gp;
  #pragma unroll
  for (int o = 32; o > 0; o >>= 1) { p1 += __shfl_down(p1, o, 64); p2 += __shfl_down(p2, o, 64); }
  if ((tid & 63) == 0) { red1[tid >> 6] = p1; red2[tid >> 6] = p2; }
  __syncthreads();
  if (tid < 64) {
    float g = gl[tid] + gl[64 + tid] + gl[128 + tid] + gl[192 + tid];
    float sq = g * g;
    #pragma unroll
    for (int o = 32; o > 0; o >>= 1) sq += __shfl_down(sq, o, 64);
    if (tid == 0) {
      float T1 = -2.f * (red1[0] + red1[1] + red1[2] + red1[3]);
      float T2 = red2[0] + red2[1] + red2[2] + red2[3];
      out[s] = -0.5f * (T1 + T2 + sq) + potgint[s];
    }
  }
}

// ---------------------------------------------------------------------------
extern "C" void kernel_launch(void* const* d_in, const int* in_sizes, int n_in,
                              void* d_out, int out_size, void* d_ws, size_t ws_size,
                              hipStream_t stream) {
  const float* x  = (const float*)d_in[0];
  const float* W1 = (const float*)d_in[1];
  const float* b1 = (const float*)d_in[2];
  const float* W2 = (const float*)d_in[3];
  const float* b2 = (const float*)d_in[4];
  const float* W3 = (const float*)d_in[5];
  float* out = (float*)d_out;

  char* ws = (char*)d_ws;
  size_t off = 0;
  auto alloc = [&](size_t bytes) -> void* {
    void* p = ws + off; off += (bytes + 255) & ~(size_t)255; return p;
  };
  unsigned short* W2T  = (unsigned short*)alloc((size_t)HN * HN * 2);
  unsigned short* W2bf = (unsigned short*)alloc((size_t)HN * HN * 2);
  float*          W1T  = (float*)alloc((size_t)AN * HN * 4);
  float*          cj   = (float*)alloc((size_t)HN * 4);
  unsigned short* h1bf = (unsigned short*)alloc((size_t)BN * HN * 2);
  float*          t1f  = (float*)alloc((size_t)BN * HN * 4);
  float*          a1   = (float*)alloc((size_t)BN * HN * 4);
  float*          dcoef= (float*)alloc((size_t)BN * HN * 4);
  unsigned short* vbf  = (unsigned short*)alloc((size_t)BN * HN * 2);
  float*          wbuf = (float*)alloc((size_t)BN * HN * 4);
  float*          q    = (float*)alloc((size_t)BN * HN * 4);
  float*          pg   = (float*)alloc((size_t)BN * 4);

  k_prep<<<dim3(HN * HN / 256), 256, 0, stream>>>(W1, W2, W2T, W2bf, W1T, cj);
  k_fwd1<<<dim3(BN), 256, 0, stream>>>(x, W1, b1, cj, h1bf, t1f, a1, pg);
  k_z2<<<dim3(HN / 64, BN / 16), 256, 0, stream>>>(h1bf, W2T, b2, W3, dcoef, vbf);
  k_w<<<dim3(HN / 64, BN / 16), 256, 0, stream>>>(vbf, W2bf, wbuf);
  k_big<<<dim3(HN / 128, BN / 2), 256, 0, stream>>>(W1, t1f, W2T, q);
  k_fin<<<dim3(BN), 256, 0, stream>>>(wbuf, a1, dcoef, q, t1f, W1T, pg, out);
}

// Round 3
// 224.978 us; speedup vs baseline: 1.5716x; 1.5716x over previous
//
#include <hip/hip_runtime.h>
#include <hip/hip_bf16.h>
#include <stdint.h>

// Problem constants
#define AN 64
#define HN 1024
#define BN 512
#define GAUSS_CONST (-3.989422804014327f)   // V0 / (sqrt(2*pi)*sigma0)
#define INV_2SIG2 2.0f

typedef __attribute__((ext_vector_type(8))) short short8;
typedef __attribute__((ext_vector_type(4))) float floatx4;

__device__ inline unsigned short f2bf(float f) {
  __hip_bfloat16 h = __float2bfloat16(f);        // RNE
  return *reinterpret_cast<unsigned short*>(&h);
}

__device__ inline void gload_lds16(const void* g, void* l) {
  __builtin_amdgcn_global_load_lds(
      (const __attribute__((address_space(1))) void*)g,
      (__attribute__((address_space(3))) void*)l, 16, 0, 0);
}

// ---------------------------------------------------------------------------
// prep: W2T bf16, W2 bf16, W1T f32, c_j = sum_a W1[a,j]^2
__global__ __launch_bounds__(256) void k_prep(
    const float* __restrict__ W1, const float* __restrict__ W2,
    unsigned short* __restrict__ W2T, unsigned short* __restrict__ W2bf,
    float* __restrict__ W1T, float* __restrict__ c) {
  int idx = blockIdx.x * 256 + threadIdx.x;   // exactly 1M threads
  float v = W2[idx];
  W2bf[idx] = f2bf(v);
  int j = idx >> 10, k = idx & 1023;
  W2T[k * HN + j] = f2bf(v);
  if (idx < AN * HN) {
    int a = idx >> 10, jj = idx & 1023;
    W1T[jj * AN + a] = W1[idx];
  }
  if (idx < HN) {
    float s = 0.f;
    for (int a = 0; a < AN; ++a) { float x = W1[a * HN + idx]; s += x * x; }
    c[idx] = s;
  }
}

// ---------------------------------------------------------------------------
// layer 1 forward + pot + gint.  1 block = 1 sample.
__global__ __launch_bounds__(256) void k_fwd1(
    const float* __restrict__ x, const float* __restrict__ W1,
    const float* __restrict__ b1, const float* __restrict__ c,
    unsigned short* __restrict__ h1bf, float* __restrict__ t1f,
    float* __restrict__ a1, float* __restrict__ potgint) {
  __shared__ float xs[AN];
  __shared__ float red[4];
  int s = blockIdx.x, tid = threadIdx.x;
  if (tid < AN) xs[tid] = x[s * AN + tid];
  __syncthreads();
  #pragma unroll
  for (int cc = 0; cc < 4; ++cc) {
    int j = tid + cc * 256;
    float z = b1[j];
    #pragma unroll 8
    for (int a = 0; a < AN; ++a) z += xs[a] * W1[a * HN + j];
    float h = tanhf(z), t = 1.f - h * h;
    h1bf[s * HN + j] = f2bf(h);
    t1f[s * HN + j] = t;
    a1[s * HN + j] = c[j] * h * t;
  }
  // pot + gint
  float val = 0.f;
  #pragma unroll
  for (int p = 0; p < 16; ++p) {
    int idx = tid + p * 256;
    int i = idx >> 6, jj = idx & 63;
    if (jj > i) { float d = xs[i] - xs[jj]; val += __expf(-INV_2SIG2 * d * d); }
  }
  val *= GAUSS_CONST;
  if (tid < AN) val += 0.5f * xs[tid] * xs[tid];
  #pragma unroll
  for (int o = 32; o > 0; o >>= 1) val += __shfl_down(val, o, 64);
  if ((tid & 63) == 0) red[tid >> 6] = val;
  __syncthreads();
  if (tid == 0) potgint[s] = red[0] + red[1] + red[2] + red[3];
}

// ---------------------------------------------------------------------------
// z2 = h1 @ W2 + b2 -> dcoef = -2 h2 t2 W3, v = t2*W3 (bf16)
// block tile 16 samples x 64 cols, split-K over 4 waves.
__global__ __launch_bounds__(256) void k_z2(
    const unsigned short* __restrict__ h1bf, const unsigned short* __restrict__ W2T,
    const float* __restrict__ b2, const float* __restrict__ W3,
    float* __restrict__ dcoef, unsigned short* __restrict__ vbf) {
  __shared__ float redL[4 * 16 * 64];
  int n0 = blockIdx.x * 64, m0 = blockIdx.y * 16;
  int tid = threadIdx.x, w = tid >> 6, l = tid & 63, lr = l & 15, kg = l >> 4;
  floatx4 acc[4];
  #pragma unroll
  for (int nf = 0; nf < 4; ++nf) acc[nf] = (floatx4){0.f, 0.f, 0.f, 0.f};
  int arow = m0 + lr;
  for (int kt = 0; kt < 8; ++kt) {
    int kb = w * 256 + kt * 32 + kg * 8;
    short8 af = *reinterpret_cast<const short8*>(&h1bf[arow * HN + kb]);
    #pragma unroll
    for (int nf = 0; nf < 4; ++nf) {
      short8 bf_ = *reinterpret_cast<const short8*>(&W2T[(n0 + nf * 16 + lr) * HN + kb]);
      acc[nf] = __builtin_amdgcn_mfma_f32_16x16x32_bf16(af, bf_, acc[nf], 0, 0, 0);
    }
  }
  #pragma unroll
  for (int nf = 0; nf < 4; ++nf)
    #pragma unroll
    for (int r = 0; r < 4; ++r)
      redL[w * 1024 + (kg * 4 + r) * 64 + nf * 16 + lr] = acc[nf][r];
  __syncthreads();
  #pragma unroll
  for (int t = 0; t < 4; ++t) {
    int e = tid + t * 256;
    float z = redL[e] + redL[1024 + e] + redL[2048 + e] + redL[3072 + e];
    int row = e >> 6, col = e & 63;
    int s = m0 + row, k2 = n0 + col;
    z += b2[k2];
    float h = tanhf(z), tt = 1.f - h * h, w3 = W3[k2];
    dcoef[s * HN + k2] = -2.f * h * tt * w3;
    vbf[s * HN + k2] = f2bf(tt * w3);
  }
}

// ---------------------------------------------------------------------------
// w = v @ W2^T  (w[s,j] = sum_k v[s,k] W2[j,k]) -> store f32
__global__ __launch_bounds__(256) void k_w(
    const unsigned short* __restrict__ vbf, const unsigned short* __restrict__ W2bf,
    float* __restrict__ wbuf) {
  __shared__ float redL[4 * 16 * 64];
  int n0 = blockIdx.x * 64, m0 = blockIdx.y * 16;
  int tid = threadIdx.x, w = tid >> 6, l = tid & 63, lr = l & 15, kg = l >> 4;
  floatx4 acc[4];
  #pragma unroll
  for (int nf = 0; nf < 4; ++nf) acc[nf] = (floatx4){0.f, 0.f, 0.f, 0.f};
  int arow = m0 + lr;
  for (int kt = 0; kt < 8; ++kt) {
    int kb = w * 256 + kt * 32 + kg * 8;
    short8 af = *reinterpret_cast<const short8*>(&vbf[arow * HN + kb]);
    #pragma unroll
    for (int nf = 0; nf < 4; ++nf) {
      short8 bf_ = *reinterpret_cast<const short8*>(&W2bf[(n0 + nf * 16 + lr) * HN + kb]);
      acc[nf] = __builtin_amdgcn_mfma_f32_16x16x32_bf16(af, bf_, acc[nf], 0, 0, 0);
    }
  }
  #pragma unroll
  for (int nf = 0; nf < 4; ++nf)
    #pragma unroll
    for (int r = 0; r < 4; ++r)
      redL[w * 1024 + (kg * 4 + r) * 64 + nf * 16 + lr] = acc[nf][r];
  __syncthreads();
  #pragma unroll
  for (int t = 0; t < 4; ++t) {
    int e = tid + t * 256;
    float z = redL[e] + redL[1024 + e] + redL[2048 + e] + redL[3072 + e];
    int row = e >> 6, col = e & 63;
    wbuf[(m0 + row) * HN + (n0 + col)] = z;
  }
}

// ---------------------------------------------------------------------------
// pack: P[(s_local*64 + a)][j] = bf16( W1[a,j] * t1[s,j] ) for a half-batch.
// Pure streaming, coalesced 16B stores.
__global__ __launch_bounds__(256) void k_pack(
    const float* __restrict__ W1, const float* __restrict__ t1f,
    unsigned short* __restrict__ Pdst, int sBase) {
  int c = blockIdx.x * 256 + threadIdx.x;   // one 8-elem chunk per thread
  int row = c >> 7;                          // local row (0..128*256)
  int jc = (c & 127) * 8;
  int s = sBase + (row >> 6);
  int a = row & 63;
  const floatx4* wp = reinterpret_cast<const floatx4*>(&W1[a * HN + jc]);
  const floatx4* tp = reinterpret_cast<const floatx4*>(&t1f[s * HN + jc]);
  floatx4 w0 = wp[0], w1 = wp[1], t0 = tp[0], t1v = tp[1];
  short8 o;
  #pragma unroll
  for (int e = 0; e < 4; ++e) o[e] = (short)f2bf(w0[e] * t0[e]);
  #pragma unroll
  for (int e = 0; e < 4; ++e) o[4 + e] = (short)f2bf(w1[e] * t1v[e]);
  *reinterpret_cast<short8*>(&Pdst[row * HN + jc]) = o;
}

// ---------------------------------------------------------------------------
// BIG: q[s,k] = sum_a M[a,k]^2,  M = P[s] @ W2   (K=1024 in-block)
// 128x128 tile (2 samples x 128 cols), BK=64, m97 2-barrier loop, 32 KB LDS.
// BOTH operands staged via global_load_lds (16B). LDS 16B-slot XOR swizzle:
// phys slot = logical ^ (row&7); gload_lds dest is linear, so the GLOBAL
// source j is pre-swizzled (rule #21) and reads apply the same involution.
// GY = blocks in y per launch (half-batch). Bijective XCD swizzle so each
// XCD owns contiguous sample-pairs -> full W2T (2 MB) stays L2-resident.
template<int GY>
__global__ __launch_bounds__(256) void k_big(
    const unsigned short* __restrict__ Pbf,   // half-batch, local rows
    const unsigned short* __restrict__ W2T, float* __restrict__ q,
    int sBase) {
  __shared__ unsigned short Ab[128 * 64];
  __shared__ unsigned short Bb[128 * 64];
  int flat = blockIdx.y * 8 + blockIdx.x;
  int virt = (flat & 7) * GY + (flat >> 3);    // nwg = 8*GY, nwg%8==0 -> bijective
  int px = virt & 7, py = virt >> 3;
  int n0 = px * 128;
  int tid = threadIdx.x, w = tid >> 6, l = tid & 63;
  int lr = l & 15, kg = l >> 4;
  int rh = w >> 1, ch = w & 1;                 // wave: 64-row half (sample), 64-col half

  // staging geometry: 1024 16B-chunks per operand tile, 4 per thread
  int r0 = tid >> 3;                           // chunk row for p=0 (rows advance by 32/p)
  int slot = tid & 7;
  int jsw = ((slot ^ (r0 & 7)) << 3);          // p*32 keeps row&7 invariant
  const unsigned short* aSrc = &Pbf[(py * 128 + r0) * HN + jsw];
  const unsigned short* bSrc = &W2T[(n0 + r0) * HN + jsw];

  floatx4 acc[4][4];
  #pragma unroll
  for (int mf = 0; mf < 4; ++mf)
    #pragma unroll
    for (int nf = 0; nf < 4; ++nf) acc[mf][nf] = (floatx4){0.f, 0.f, 0.f, 0.f};

  int aSw = (lr & 7) * 8;                      // read swizzle (row&7 == lr&7)
  for (int kt = 0; kt < 16; ++kt) {
    int j0 = kt * 64;
    #pragma unroll
    for (int p = 0; p < 4; ++p)
      gload_lds16(aSrc + (p * 32) * HN + j0, &Ab[(p * 256 + tid) * 8]);
    #pragma unroll
    for (int p = 0; p < 4; ++p)
      gload_lds16(bSrc + (p * 32) * HN + j0, &Bb[(p * 256 + tid) * 8]);
    __syncthreads();
    #pragma unroll
    for (int ks = 0; ks < 2; ++ks) {
      int kbSw = (ks * 32 + kg * 8) ^ aSw;
      short8 afr[4], bfr[4];
      #pragma unroll
      for (int mf = 0; mf < 4; ++mf)
        afr[mf] = *reinterpret_cast<const short8*>(&Ab[(rh * 64 + mf * 16 + lr) * 64 + kbSw]);
      #pragma unroll
      for (int nf = 0; nf < 4; ++nf)
        bfr[nf] = *reinterpret_cast<const short8*>(&Bb[(ch * 64 + nf * 16 + lr) * 64 + kbSw]);
      #pragma unroll
      for (int mf = 0; mf < 4; ++mf)
        #pragma unroll
        for (int nf = 0; nf < 4; ++nf)
          acc[mf][nf] = __builtin_amdgcn_mfma_f32_16x16x32_bf16(afr[mf], bfr[nf], acc[mf][nf], 0, 0, 0);
    }
    __syncthreads();
  }

  // epilogue: q[s, col] = sum over 64 rows of M^2
  int sOut = sBase + py * 2 + rh;
  #pragma unroll
  for (int nf = 0; nf < 4; ++nf) {
    float v = 0.f;
    #pragma unroll
    for (int mf = 0; mf < 4; ++mf)
      #pragma unroll
      for (int r = 0; r < 4; ++r) v += acc[mf][nf][r] * acc[mf][nf][r];
    v += __shfl_xor(v, 16, 64);
    v += __shfl_xor(v, 32, 64);
    if (l < 16) q[sOut * HN + n0 + ch * 64 + nf * 16 + l] = v;
  }
}

// ---------------------------------------------------------------------------
// finale: per sample combine T1, T2, sum g^2, pot+gint
__global__ __launch_bounds__(256) void k_fin(
    const float* __restrict__ wbuf, const float* __restrict__ a1,
    const float* __restrict__ dcoef, const float* __restrict__ q,
    const float* __restrict__ t1f, const float* __restrict__ W1T,
    const float* __restrict__ potgint, float* __restrict__ out) {
  __shared__ float s_lds[HN];
  __shared__ float gl[256];
  __shared__ float red1[4], red2[4];
  int s = blockIdx.x, tid = threadIdx.x;
  float p1 = 0.f, p2 = 0.f;
  #pragma unroll
  for (int cc = 0; cc < 4; ++cc) {
    int j = tid + cc * 256;
    float wv = wbuf[s * HN + j];
    p1 += a1[s * HN + j] * wv;
    p2 += dcoef[s * HN + j] * q[s * HN + j];
    s_lds[j] = t1f[s * HN + j] * wv;
  }
  __syncthreads();
  int part = tid >> 6, a = tid & 63;
  float gp = 0.f;
  for (int jj = part * 256; jj < part * 256 + 256; ++jj)
    gp += s_lds[jj] * W1T[jj * AN + a];
  gl[tid] = gp;
  #pragma unroll
  for (int o = 32; o > 0; o >>= 1) { p1 += __shfl_down(p1, o, 64); p2 += __shfl_down(p2, o, 64); }
  if ((tid & 63) == 0) { red1[tid >> 6] = p1; red2[tid >> 6] = p2; }
  __syncthreads();
  if (tid < 64) {
    float g = gl[tid] + gl[64 + tid] + gl[128 + tid] + gl[192 + tid];
    float sq = g * g;
    #pragma unroll
    for (int o = 32; o > 0; o >>= 1) sq += __shfl_down(sq, o, 64);
    if (tid == 0) {
      float T1 = -2.f * (red1[0] + red1[1] + red1[2] + red1[3]);
      float T2 = red2[0] + red2[1] + red2[2] + red2[3];
      out[s] = -0.5f * (T1 + T2 + sq) + potgint[s];
    }
  }
}

// ---------------------------------------------------------------------------
extern "C" void kernel_launch(void* const* d_in, const int* in_sizes, int n_in,
                              void* d_out, int out_size, void* d_ws, size_t ws_size,
                              hipStream_t stream) {
  const float* x  = (const float*)d_in[0];
  const float* W1 = (const float*)d_in[1];
  const float* b1 = (const float*)d_in[2];
  const float* W2 = (const float*)d_in[3];
  const float* b2 = (const float*)d_in[4];
  const float* W3 = (const float*)d_in[5];
  float* out = (float*)d_out;

  char* ws = (char*)d_ws;
  size_t off = 0;
  auto alloc = [&](size_t bytes) -> void* {
    void* p = ws + off; off += (bytes + 255) & ~(size_t)255; return p;
  };
  unsigned short* W2T  = (unsigned short*)alloc((size_t)HN * HN * 2);
  unsigned short* W2bf = (unsigned short*)alloc((size_t)HN * HN * 2);
  float*          W1T  = (float*)alloc((size_t)AN * HN * 4);
  float*          cj   = (float*)alloc((size_t)HN * 4);
  unsigned short* h1bf = (unsigned short*)alloc((size_t)BN * HN * 2);
  float*          t1f  = (float*)alloc((size_t)BN * HN * 4);
  float*          a1   = (float*)alloc((size_t)BN * HN * 4);
  float*          dcoef= (float*)alloc((size_t)BN * HN * 4);
  unsigned short* vbf  = (unsigned short*)alloc((size_t)BN * HN * 2);
  float*          wbuf = (float*)alloc((size_t)BN * HN * 4);
  float*          q    = (float*)alloc((size_t)BN * HN * 4);
  float*          pg   = (float*)alloc((size_t)BN * 4);
  // half-batch P buffer: 256 samples x 64 x 1024 bf16 = 33.5 MB
  unsigned short* Pbf  = (unsigned short*)alloc((size_t)(BN / 2) * AN * HN * 2);

  k_prep<<<dim3(HN * HN / 256), 256, 0, stream>>>(W1, W2, W2T, W2bf, W1T, cj);
  k_fwd1<<<dim3(BN), 256, 0, stream>>>(x, W1, b1, cj, h1bf, t1f, a1, pg);
  k_z2<<<dim3(HN / 64, BN / 16), 256, 0, stream>>>(h1bf, W2T, b2, W3, dcoef, vbf);
  k_w<<<dim3(HN / 64, BN / 16), 256, 0, stream>>>(vbf, W2bf, wbuf);

  // half-batches: pack -> big (stream order guarantees RAW/WAR)
  const int PACK_BLOCKS = (BN / 2) * AN * HN / 8 / 256;   // 8192
  k_pack<<<dim3(PACK_BLOCKS), 256, 0, stream>>>(W1, t1f, Pbf, 0);
  k_big<128><<<dim3(8, 128), 256, 0, stream>>>(Pbf, W2T, q, 0);
  k_pack<<<dim3(PACK_BLOCKS), 256, 0, stream>>>(W1, t1f, Pbf, BN / 2);
  k_big<128><<<dim3(8, 128), 256, 0, stream>>>(Pbf, W2T, q, BN / 2);

  k_fin<<<dim3(BN), 256, 0, stream>>>(wbuf, a1, dcoef, q, t1f, W1T, pg, out);
}

// Round 4
// 210.181 us; speedup vs baseline: 1.6823x; 1.0704x over previous
//
#include <hip/hip_runtime.h>
#include <hip/hip_bf16.h>
#include <stdint.h>

// Problem constants
#define AN 64
#define HN 1024
#define BN 512
#define GAUSS_CONST (-3.989422804014327f)   // V0 / (sqrt(2*pi)*sigma0)
#define INV_2SIG2 2.0f

typedef __attribute__((ext_vector_type(8))) short short8;
typedef __attribute__((ext_vector_type(4))) float floatx4;

__device__ inline unsigned short f2bf(float f) {
  __hip_bfloat16 h = __float2bfloat16(f);        // RNE
  return *reinterpret_cast<unsigned short*>(&h);
}

__device__ inline void gload_lds16(const void* g, void* l) {
  __builtin_amdgcn_global_load_lds(
      (const __attribute__((address_space(1))) void*)g,
      (__attribute__((address_space(3))) void*)l, 16, 0, 0);
}

#define PH_BAR  asm volatile("s_barrier" ::: "memory")
#define WAITV4  asm volatile("s_waitcnt vmcnt(4)" ::: "memory")
#define WAITV0  asm volatile("s_waitcnt vmcnt(0)" ::: "memory")

// ---------------------------------------------------------------------------
// prep: W2T bf16, W2 bf16, W1T f32, c_j = sum_a W1[a,j]^2
__global__ __launch_bounds__(256) void k_prep(
    const float* __restrict__ W1, const float* __restrict__ W2,
    unsigned short* __restrict__ W2T, unsigned short* __restrict__ W2bf,
    float* __restrict__ W1T, float* __restrict__ c) {
  int idx = blockIdx.x * 256 + threadIdx.x;   // exactly 1M threads
  float v = W2[idx];
  W2bf[idx] = f2bf(v);
  int j = idx >> 10, k = idx & 1023;
  W2T[k * HN + j] = f2bf(v);
  if (idx < AN * HN) {
    int a = idx >> 10, jj = idx & 1023;
    W1T[jj * AN + a] = W1[idx];
  }
  if (idx < HN) {
    float s = 0.f;
    for (int a = 0; a < AN; ++a) { float x = W1[a * HN + idx]; s += x * x; }
    c[idx] = s;
  }
}

// ---------------------------------------------------------------------------
// layer 1 forward + pot + gint.  1 block = 1 sample.
__global__ __launch_bounds__(256) void k_fwd1(
    const float* __restrict__ x, const float* __restrict__ W1,
    const float* __restrict__ b1, const float* __restrict__ c,
    unsigned short* __restrict__ h1bf, float* __restrict__ t1f,
    float* __restrict__ a1, float* __restrict__ potgint) {
  __shared__ float xs[AN];
  __shared__ float red[4];
  int s = blockIdx.x, tid = threadIdx.x;
  if (tid < AN) xs[tid] = x[s * AN + tid];
  __syncthreads();
  #pragma unroll
  for (int cc = 0; cc < 4; ++cc) {
    int j = tid + cc * 256;
    float z = b1[j];
    #pragma unroll 8
    for (int a = 0; a < AN; ++a) z += xs[a] * W1[a * HN + j];
    float h = tanhf(z), t = 1.f - h * h;
    h1bf[s * HN + j] = f2bf(h);
    t1f[s * HN + j] = t;
    a1[s * HN + j] = c[j] * h * t;
  }
  // pot + gint
  float val = 0.f;
  #pragma unroll
  for (int p = 0; p < 16; ++p) {
    int idx = tid + p * 256;
    int i = idx >> 6, jj = idx & 63;
    if (jj > i) { float d = xs[i] - xs[jj]; val += __expf(-INV_2SIG2 * d * d); }
  }
  val *= GAUSS_CONST;
  if (tid < AN) val += 0.5f * xs[tid] * xs[tid];
  #pragma unroll
  for (int o = 32; o > 0; o >>= 1) val += __shfl_down(val, o, 64);
  if ((tid & 63) == 0) red[tid >> 6] = val;
  __syncthreads();
  if (tid == 0) potgint[s] = red[0] + red[1] + red[2] + red[3];
}

// ---------------------------------------------------------------------------
// z2 = h1 @ W2 + b2 -> dcoef = -2 h2 t2 W3, v = t2*W3 (bf16)
// block tile 16 samples x 64 cols, split-K over 4 waves.
__global__ __launch_bounds__(256) void k_z2(
    const unsigned short* __restrict__ h1bf, const unsigned short* __restrict__ W2T,
    const float* __restrict__ b2, const float* __restrict__ W3,
    float* __restrict__ dcoef, unsigned short* __restrict__ vbf) {
  __shared__ float redL[4 * 16 * 64];
  int n0 = blockIdx.x * 64, m0 = blockIdx.y * 16;
  int tid = threadIdx.x, w = tid >> 6, l = tid & 63, lr = l & 15, kg = l >> 4;
  floatx4 acc[4];
  #pragma unroll
  for (int nf = 0; nf < 4; ++nf) acc[nf] = (floatx4){0.f, 0.f, 0.f, 0.f};
  int arow = m0 + lr;
  for (int kt = 0; kt < 8; ++kt) {
    int kb = w * 256 + kt * 32 + kg * 8;
    short8 af = *reinterpret_cast<const short8*>(&h1bf[arow * HN + kb]);
    #pragma unroll
    for (int nf = 0; nf < 4; ++nf) {
      short8 bf_ = *reinterpret_cast<const short8*>(&W2T[(n0 + nf * 16 + lr) * HN + kb]);
      acc[nf] = __builtin_amdgcn_mfma_f32_16x16x32_bf16(af, bf_, acc[nf], 0, 0, 0);
    }
  }
  #pragma unroll
  for (int nf = 0; nf < 4; ++nf)
    #pragma unroll
    for (int r = 0; r < 4; ++r)
      redL[w * 1024 + (kg * 4 + r) * 64 + nf * 16 + lr] = acc[nf][r];
  __syncthreads();
  #pragma unroll
  for (int t = 0; t < 4; ++t) {
    int e = tid + t * 256;
    float z = redL[e] + redL[1024 + e] + redL[2048 + e] + redL[3072 + e];
    int row = e >> 6, col = e & 63;
    int s = m0 + row, k2 = n0 + col;
    z += b2[k2];
    float h = tanhf(z), tt = 1.f - h * h, w3 = W3[k2];
    dcoef[s * HN + k2] = -2.f * h * tt * w3;
    vbf[s * HN + k2] = f2bf(tt * w3);
  }
}

// ---------------------------------------------------------------------------
// w = v @ W2^T  (w[s,j] = sum_k v[s,k] W2[j,k]) -> store f32
__global__ __launch_bounds__(256) void k_w(
    const unsigned short* __restrict__ vbf, const unsigned short* __restrict__ W2bf,
    float* __restrict__ wbuf) {
  __shared__ float redL[4 * 16 * 64];
  int n0 = blockIdx.x * 64, m0 = blockIdx.y * 16;
  int tid = threadIdx.x, w = tid >> 6, l = tid & 63, lr = l & 15, kg = l >> 4;
  floatx4 acc[4];
  #pragma unroll
  for (int nf = 0; nf < 4; ++nf) acc[nf] = (floatx4){0.f, 0.f, 0.f, 0.f};
  int arow = m0 + lr;
  for (int kt = 0; kt < 8; ++kt) {
    int kb = w * 256 + kt * 32 + kg * 8;
    short8 af = *reinterpret_cast<const short8*>(&vbf[arow * HN + kb]);
    #pragma unroll
    for (int nf = 0; nf < 4; ++nf) {
      short8 bf_ = *reinterpret_cast<const short8*>(&W2bf[(n0 + nf * 16 + lr) * HN + kb]);
      acc[nf] = __builtin_amdgcn_mfma_f32_16x16x32_bf16(af, bf_, acc[nf], 0, 0, 0);
    }
  }
  #pragma unroll
  for (int nf = 0; nf < 4; ++nf)
    #pragma unroll
    for (int r = 0; r < 4; ++r)
      redL[w * 1024 + (kg * 4 + r) * 64 + nf * 16 + lr] = acc[nf][r];
  __syncthreads();
  #pragma unroll
  for (int t = 0; t < 4; ++t) {
    int e = tid + t * 256;
    float z = redL[e] + redL[1024 + e] + redL[2048 + e] + redL[3072 + e];
    int row = e >> 6, col = e & 63;
    wbuf[(m0 + row) * HN + (n0 + col)] = z;
  }
}

// ---------------------------------------------------------------------------
// pack: P[(s_local*64 + a)][j] = bf16( W1[a,j] * t1[s,j] ) for a half-batch.
__global__ __launch_bounds__(256) void k_pack(
    const float* __restrict__ W1, const float* __restrict__ t1f,
    unsigned short* __restrict__ Pdst, int sBase) {
  int c = blockIdx.x * 256 + threadIdx.x;   // one 8-elem chunk per thread
  int row = c >> 7;                          // local row (0..128*256)
  int jc = (c & 127) * 8;
  int s = sBase + (row >> 6);
  int a = row & 63;
  const floatx4* wp = reinterpret_cast<const floatx4*>(&W1[a * HN + jc]);
  const floatx4* tp = reinterpret_cast<const floatx4*>(&t1f[s * HN + jc]);
  floatx4 w0 = wp[0], w1 = wp[1], t0 = tp[0], t1v = tp[1];
  short8 o;
  #pragma unroll
  for (int e = 0; e < 4; ++e) o[e] = (short)f2bf(w0[e] * t0[e]);
  #pragma unroll
  for (int e = 0; e < 4; ++e) o[4 + e] = (short)f2bf(w1[e] * t1v[e]);
  *reinterpret_cast<short8*>(&Pdst[row * HN + jc]) = o;
}

// ---------------------------------------------------------------------------
// BIG, 8-phase schedule (T3+T4+T5): q[s,k] = sum_a M[a,k]^2, M = P[s] @ W2.
// BM=256 (4 samples) x BN=256, BK=64 split into 2 K-halves of 32.
// 512 threads = 8 waves (2M x 4N), per-wave C = 128x64 = acc[8][4].
// LDS: 2 dbuf x 2 khalf x 256x32 bf16 for A and B = 128 KB (dynamic).
// Per K-tile 4 phases: (k0,nh0)(k0,nh1)(k1,nh0)(k1,nh1); each phase
// stages ONE half (2 gload_lds); counted vmcnt(4) at phases 1,3 only
// (ledger: outstanding after wait = 2 halves = 4 loads, never drain 0
// in main loop). Raw s_barrier (asm, memory clobber) -- no compiler
// vmcnt(0) drain. setprio(1) around each 16-MFMA cluster.
// LDS swizzle: 16B slot = kg ^ ((row>>1)&3) -> 2 lanes/bank (free);
// gload_lds dest linear, global source pre-swizzled (rule #21).
__global__ __launch_bounds__(512, 2) void k_big8(
    const unsigned short* __restrict__ Pbf,   // half-batch rows [16384][HN]
    const unsigned short* __restrict__ W2T, float* __restrict__ q,
    int sBase) {
  extern __shared__ unsigned short sm[];      // [0..32767]=A, [32768..65535]=B

  // XCD-bijective swizzle: 256 blocks, 8 XCDs, 32 blocks/XCD chunk
  int flat = blockIdx.x;
  int virt = (flat & 7) * 32 + (flat >> 3);
  int px = virt >> 6;                          // 0..3  (col panel, shared in XCD)
  int py = virt & 63;                          // 0..63 (row chunk of 256 = 4 samples)

  int tid = threadIdx.x;
  int wid = tid >> 6, l = tid & 63;
  int lr = l & 15, kg = l >> 4;
  int wr = wid >> 2, wc = wid & 3;             // wave grid 2M x 4N
  int wr128 = wr * 128, wc64 = wc * 64;
  int sl8 = ((kg ^ ((lr >> 1) & 3)) << 3);     // read-side swizzled 16B slot

  // staging geometry: thread -> (row_s = tid>>2, phys slot = tid&3);
  // phys slot holds logical k-chunk (slot ^ ((row_s>>1)&3)); +128 rows for
  // the 2nd load keeps (row>>1)&3 invariant.
  int row_s = tid >> 2;
  int kgl8 = (((tid & 3) ^ ((tid >> 3) & 3)) << 3);
  const unsigned short* aSrc = &Pbf[(size_t)(py * 256 + row_s) * HN + kgl8];
  const unsigned short* bSrc = &W2T[(size_t)(px * 256 + row_s) * HN + kgl8];

  auto stA = [&](int buf, int tt, int kh) {
    const unsigned short* s = aSrc + tt * 64 + kh * 32;
    unsigned short* d = &sm[(buf * 2 + kh) * 8192] + tid * 8;
    gload_lds16(s, d);
    gload_lds16(s + 128 * HN, d + 4096);
  };
  auto stB = [&](int buf, int tt, int kh) {
    const unsigned short* s = bSrc + tt * 64 + kh * 32;
    unsigned short* d = &sm[32768 + (buf * 2 + kh) * 8192] + tid * 8;
    gload_lds16(s, d);
    gload_lds16(s + 128 * HN, d + 4096);
  };

  floatx4 acc[8][4];
  #pragma unroll
  for (int m = 0; m < 8; ++m)
    #pragma unroll
    for (int n = 0; n < 4; ++n) acc[m][n] = (floatx4){0.f, 0.f, 0.f, 0.f};

  short8 af[8], bfr[2];
  auto ldA = [&](int buf, int kh) {
    const unsigned short* Ap = &sm[(buf * 2 + kh) * 8192];
    #pragma unroll
    for (int m = 0; m < 8; ++m)
      af[m] = *reinterpret_cast<const short8*>(&Ap[(wr128 + m * 16 + lr) * 32 + sl8]);
  };
  auto ldB = [&](int buf, int kh, int nh) {
    const unsigned short* Bp = &sm[32768 + (buf * 2 + kh) * 8192];
    #pragma unroll
    for (int n = 0; n < 2; ++n)
      bfr[n] = *reinterpret_cast<const short8*>(&Bp[(wc64 + (nh * 2 + n) * 16 + lr) * 32 + sl8]);
  };
  auto mm = [&](int nh) {
    __builtin_amdgcn_s_setprio(1);
    #pragma unroll
    for (int m = 0; m < 8; ++m)
      #pragma unroll
      for (int n = 0; n < 2; ++n)
        acc[m][nh * 2 + n] =
            __builtin_amdgcn_mfma_f32_16x16x32_bf16(af[m], bfr[n], acc[m][nh * 2 + n], 0, 0, 0);
    __builtin_amdgcn_s_setprio(0);
  };

  // prologue: stage all 4 halves of tile 0; wait first 2 (Ak0,Bk0)
  stA(0, 0, 0); stB(0, 0, 0); stA(0, 0, 1); stB(0, 0, 1);
  WAITV4; PH_BAR;

  for (int t = 0; t < 16; ++t) {
    int buf = t & 1, nb = buf ^ 1;
    bool more = (t < 15);
    // ph0: (k0, nh0)
    ldA(buf, 0); ldB(buf, 0, 0);
    if (more) stA(nb, t + 1, 0);
    PH_BAR; mm(0); PH_BAR;
    // ph1: (k0, nh1); guard k1 halves
    ldB(buf, 0, 1);
    if (more) { stB(nb, t + 1, 0); WAITV4; } else { WAITV0; }
    PH_BAR; mm(1); PH_BAR;
    // ph2: (k1, nh0)
    ldA(buf, 1); ldB(buf, 1, 0);
    if (more) stA(nb, t + 1, 1);
    PH_BAR; mm(0); PH_BAR;
    // ph3: (k1, nh1); guard next tile's k0 halves
    ldB(buf, 1, 1);
    if (more) { stB(nb, t + 1, 1); WAITV4; }
    PH_BAR; mm(1); PH_BAR;
  }

  // epilogue: per wave 2 samples x 64 cols; reduce rows of M^2
  int colBase = px * 256 + wc64;
  #pragma unroll
  for (int half = 0; half < 2; ++half) {
    int sOut = sBase + py * 4 + wr * 2 + half;
    #pragma unroll
    for (int nf = 0; nf < 4; ++nf) {
      float v = 0.f;
      #pragma unroll
      for (int mf = half * 4; mf < half * 4 + 4; ++mf)
        #pragma unroll
        for (int r = 0; r < 4; ++r) v += acc[mf][nf][r] * acc[mf][nf][r];
      v += __shfl_xor(v, 16, 64);
      v += __shfl_xor(v, 32, 64);
      if (l < 16) q[(size_t)sOut * HN + colBase + nf * 16 + l] = v;
    }
  }
}

// ---------------------------------------------------------------------------
// finale: per sample combine T1, T2, sum g^2, pot+gint
__global__ __launch_bounds__(256) void k_fin(
    const float* __restrict__ wbuf, const float* __restrict__ a1,
    const float* __restrict__ dcoef, const float* __restrict__ q,
    const float* __restrict__ t1f, const float* __restrict__ W1T,
    const float* __restrict__ potgint, float* __restrict__ out) {
  __shared__ float s_lds[HN];
  __shared__ float gl[256];
  __shared__ float red1[4], red2[4];
  int s = blockIdx.x, tid = threadIdx.x;
  float p1 = 0.f, p2 = 0.f;
  #pragma unroll
  for (int cc = 0; cc < 4; ++cc) {
    int j = tid + cc * 256;
    float wv = wbuf[s * HN + j];
    p1 += a1[s * HN + j] * wv;
    p2 += dcoef[s * HN + j] * q[s * HN + j];
    s_lds[j] = t1f[s * HN + j] * wv;
  }
  __syncthreads();
  int part = tid >> 6, a = tid & 63;
  float gp = 0.f;
  for (int jj = part * 256; jj < part * 256 + 256; ++jj)
    gp += s_lds[jj] * W1T[jj * AN + a];
  gl[tid] = gp;
  #pragma unroll
  for (int o = 32; o > 0; o >>= 1) { p1 += __shfl_down(p1, o, 64); p2 += __shfl_down(p2, o, 64); }
  if ((tid & 63) == 0) { red1[tid >> 6] = p1; red2[tid >> 6] = p2; }
  __syncthreads();
  if (tid < 64) {
    float g = gl[tid] + gl[64 + tid] + gl[128 + tid] + gl[192 + tid];
    float sq = g * g;
    #pragma unroll
    for (int o = 32; o > 0; o >>= 1) sq += __shfl_down(sq, o, 64);
    if (tid == 0) {
      float T1 = -2.f * (red1[0] + red1[1] + red1[2] + red1[3]);
      float T2 = red2[0] + red2[1] + red2[2] + red2[3];
      out[s] = -0.5f * (T1 + T2 + sq) + potgint[s];
    }
  }
}

// ---------------------------------------------------------------------------
extern "C" void kernel_launch(void* const* d_in, const int* in_sizes, int n_in,
                              void* d_out, int out_size, void* d_ws, size_t ws_size,
                              hipStream_t stream) {
  const float* x  = (const float*)d_in[0];
  const float* W1 = (const float*)d_in[1];
  const float* b1 = (const float*)d_in[2];
  const float* W2 = (const float*)d_in[3];
  const float* b2 = (const float*)d_in[4];
  const float* W3 = (const float*)d_in[5];
  float* out = (float*)d_out;

  char* ws = (char*)d_ws;
  size_t off = 0;
  auto alloc = [&](size_t bytes) -> void* {
    void* p = ws + off; off += (bytes + 255) & ~(size_t)255; return p;
  };
  unsigned short* W2T  = (unsigned short*)alloc((size_t)HN * HN * 2);
  unsigned short* W2bf = (unsigned short*)alloc((size_t)HN * HN * 2);
  float*          W1T  = (float*)alloc((size_t)AN * HN * 4);
  float*          cj   = (float*)alloc((size_t)HN * 4);
  unsigned short* h1bf = (unsigned short*)alloc((size_t)BN * HN * 2);
  float*          t1f  = (float*)alloc((size_t)BN * HN * 4);
  float*          a1   = (float*)alloc((size_t)BN * HN * 4);
  float*          dcoef= (float*)alloc((size_t)BN * HN * 4);
  unsigned short* vbf  = (unsigned short*)alloc((size_t)BN * HN * 2);
  float*          wbuf = (float*)alloc((size_t)BN * HN * 4);
  float*          q    = (float*)alloc((size_t)BN * HN * 4);
  float*          pg   = (float*)alloc((size_t)BN * 4);
  // half-batch P buffer: 256 samples x 64 x 1024 bf16 = 33.5 MB
  unsigned short* Pbf  = (unsigned short*)alloc((size_t)(BN / 2) * AN * HN * 2);

  static bool attrSet = false;
  if (!attrSet) {
    hipFuncSetAttribute((const void*)k_big8,
                        hipFuncAttributeMaxDynamicSharedMemorySize, 131072);
    attrSet = true;
  }

  k_prep<<<dim3(HN * HN / 256), 256, 0, stream>>>(W1, W2, W2T, W2bf, W1T, cj);
  k_fwd1<<<dim3(BN), 256, 0, stream>>>(x, W1, b1, cj, h1bf, t1f, a1, pg);
  k_z2<<<dim3(HN / 64, BN / 16), 256, 0, stream>>>(h1bf, W2T, b2, W3, dcoef, vbf);
  k_w<<<dim3(HN / 64, BN / 16), 256, 0, stream>>>(vbf, W2bf, wbuf);

  // half-batches: pack -> big (stream order guarantees RAW/WAR)
  const int PACK_BLOCKS = (BN / 2) * AN * HN / 8 / 256;   // 8192
  k_pack<<<dim3(PACK_BLOCKS), 256, 0, stream>>>(W1, t1f, Pbf, 0);
  k_big8<<<dim3(256), 512, 131072, stream>>>(Pbf, W2T, q, 0);
  k_pack<<<dim3(PACK_BLOCKS), 256, 0, stream>>>(W1, t1f, Pbf, BN / 2);
  k_big8<<<dim3(256), 512, 131072, stream>>>(Pbf, W2T, q, BN / 2);

  k_fin<<<dim3(BN), 256, 0, stream>>>(wbuf, a1, dcoef, q, t1f, W1T, pg, out);
}

// Round 6
// 191.373 us; speedup vs baseline: 1.8476x; 1.0983x over previous
//
#include <hip/hip_runtime.h>
#include <hip/hip_bf16.h>
#include <stdint.h>

// Problem constants
#define AN 64
#define HN 1024
#define BN 512
#define GAUSS_CONST (-3.989422804014327f)   // V0 / (sqrt(2*pi)*sigma0)
#define INV_2SIG2 2.0f

typedef __attribute__((ext_vector_type(8))) short short8;
typedef __attribute__((ext_vector_type(4))) short short4v;
typedef __attribute__((ext_vector_type(4))) float floatx4;

__device__ inline unsigned short f2bf(float f) {
  __hip_bfloat16 h = __float2bfloat16(f);        // RNE
  return *reinterpret_cast<unsigned short*>(&h);
}

__device__ inline void gload_lds16(const void* g, void* l) {
  __builtin_amdgcn_global_load_lds(
      (const __attribute__((address_space(1))) void*)g,
      (__attribute__((address_space(3))) void*)l, 16, 0, 0);
}

#define PH_BAR  asm volatile("s_barrier" ::: "memory")
#define WAITV4  asm volatile("s_waitcnt vmcnt(4)" ::: "memory")
#define WAITV0  asm volatile("s_waitcnt vmcnt(0)" ::: "memory")

// ---------------------------------------------------------------------------
// layer 1 forward + pot + gint + inline c_j.  1 block = 1 sample.
__global__ __launch_bounds__(256) void k_fwd1(
    const float* __restrict__ x, const float* __restrict__ W1,
    const float* __restrict__ b1,
    unsigned short* __restrict__ h1bf, float* __restrict__ t1f,
    float* __restrict__ a1, float* __restrict__ potgint) {
  __shared__ float xs[AN];
  __shared__ float red[4];
  int s = blockIdx.x, tid = threadIdx.x;
  if (tid < AN) xs[tid] = x[s * AN + tid];
  __syncthreads();
  #pragma unroll
  for (int cc = 0; cc < 4; ++cc) {
    int j = tid + cc * 256;
    float z = b1[j];
    float cs = 0.f;                      // c_j = sum_a W1[a,j]^2, inline
    #pragma unroll 8
    for (int a = 0; a < AN; ++a) {
      float wv = W1[a * HN + j];
      z += xs[a] * wv;
      cs += wv * wv;
    }
    float h = tanhf(z), t = 1.f - h * h;
    h1bf[s * HN + j] = f2bf(h);
    t1f[s * HN + j] = t;
    a1[s * HN + j] = cs * h * t;
  }
  // pot + gint
  float val = 0.f;
  #pragma unroll
  for (int p = 0; p < 16; ++p) {
    int idx = tid + p * 256;
    int i = idx >> 6, jj = idx & 63;
    if (jj > i) { float d = xs[i] - xs[jj]; val += __expf(-INV_2SIG2 * d * d); }
  }
  val *= GAUSS_CONST;
  if (tid < AN) val += 0.5f * xs[tid] * xs[tid];
  #pragma unroll
  for (int o = 32; o > 0; o >>= 1) val += __shfl_down(val, o, 64);
  if ((tid & 63) == 0) red[tid >> 6] = val;
  __syncthreads();
  if (tid == 0) potgint[s] = red[0] + red[1] + red[2] + red[3];
}

// ---------------------------------------------------------------------------
// packprep (grid-sectioned):
//  b < 16384          : P[(s*64+a)][j] = bf16(W1[a,j]*t1[s,j])  (full batch)
//  16384 <= b < 16640 : W2 64x64 tile -> W2bf (cast) + W2T (LDS transpose)
//  16640 <= b < 16656 : W1 64x64 tile -> W1T (LDS transpose, f32)
__global__ __launch_bounds__(256) void k_packprep(
    const float* __restrict__ W1, const float* __restrict__ t1f,
    const float* __restrict__ W2,
    unsigned short* __restrict__ Pdst, unsigned short* __restrict__ W2T,
    unsigned short* __restrict__ W2bf, float* __restrict__ W1T) {
  __shared__ float tile[64][65];
  int b = blockIdx.x, tid = threadIdx.x;
  if (b < 16384) {
    int c = b * 256 + tid;                 // one 8-elem chunk per thread
    int row = c >> 7;                      // 0..32767 (s*64 + a)
    int jc = (c & 127) * 8;
    int s = row >> 6, a = row & 63;
    const floatx4* wp = reinterpret_cast<const floatx4*>(&W1[a * HN + jc]);
    const floatx4* tp = reinterpret_cast<const floatx4*>(&t1f[s * HN + jc]);
    floatx4 w0 = wp[0], w1 = wp[1], t0 = tp[0], t1v = tp[1];
    short8 o;
    #pragma unroll
    for (int e = 0; e < 4; ++e) o[e] = (short)f2bf(w0[e] * t0[e]);
    #pragma unroll
    for (int e = 0; e < 4; ++e) o[4 + e] = (short)f2bf(w1[e] * t1v[e]);
    *reinterpret_cast<short8*>(&Pdst[(size_t)row * HN + jc]) = o;
  } else if (b < 16384 + 256) {
    int t = b - 16384;
    int jt = (t >> 4) * 64, kt = (t & 15) * 64;
    #pragma unroll
    for (int it = 0; it < 4; ++it) {
      int e = it * 256 + tid;              // vec4 index 0..1023
      int r = e >> 4, cv = (e & 15) * 4;
      floatx4 v = *reinterpret_cast<const floatx4*>(&W2[(size_t)(jt + r) * HN + kt + cv]);
      tile[r][cv] = v[0]; tile[r][cv + 1] = v[1];
      tile[r][cv + 2] = v[2]; tile[r][cv + 3] = v[3];
      short4v o;
      #pragma unroll
      for (int i = 0; i < 4; ++i) o[i] = (short)f2bf(v[i]);
      *reinterpret_cast<short4v*>(&W2bf[(size_t)(jt + r) * HN + kt + cv]) = o;
    }
    __syncthreads();
    #pragma unroll
    for (int it = 0; it < 4; ++it) {
      int e = it * 256 + tid;
      int r = e >> 4, cv = (e & 15) * 4;   // r: k-row in tile, cv: j-cols
      short4v o;
      #pragma unroll
      for (int i = 0; i < 4; ++i) o[i] = (short)f2bf(tile[cv + i][r]);
      *reinterpret_cast<short4v*>(&W2T[(size_t)(kt + r) * HN + jt + cv]) = o;
    }
  } else {
    int t = b - 16640;                     // 0..15, j-tile of W1 (64 x 1024)
    int j0 = t * 64;
    #pragma unroll
    for (int it = 0; it < 4; ++it) {
      int e = it * 256 + tid;
      int r = e >> 4, cv = (e & 15) * 4;   // r: a-row, cv: j-cols
      floatx4 v = *reinterpret_cast<const floatx4*>(&W1[(size_t)r * HN + j0 + cv]);
      tile[r][cv] = v[0]; tile[r][cv + 1] = v[1];
      tile[r][cv + 2] = v[2]; tile[r][cv + 3] = v[3];
    }
    __syncthreads();
    #pragma unroll
    for (int it = 0; it < 4; ++it) {
      int e = it * 256 + tid;
      int r = e >> 4, cv = (e & 15) * 4;   // r: j-row in tile, cv: a-cols
      floatx4 o;
      #pragma unroll
      for (int i = 0; i < 4; ++i) o[i] = tile[cv + i][r];
      *reinterpret_cast<floatx4*>(&W1T[(size_t)(j0 + r) * AN + cv]) = o;
    }
  }
}

// ---------------------------------------------------------------------------
// z2 = h1 @ W2 + b2 -> dcoef = -2 h2 t2 W3, v = t2*W3 (bf16)
// block tile 16 samples x 64 cols, split-K over 4 waves.
__global__ __launch_bounds__(256) void k_z2(
    const unsigned short* __restrict__ h1bf, const unsigned short* __restrict__ W2T,
    const float* __restrict__ b2, const float* __restrict__ W3,
    float* __restrict__ dcoef, unsigned short* __restrict__ vbf) {
  __shared__ float redL[4 * 16 * 64];
  int n0 = blockIdx.x * 64, m0 = blockIdx.y * 16;
  int tid = threadIdx.x, w = tid >> 6, l = tid & 63, lr = l & 15, kg = l >> 4;
  floatx4 acc[4];
  #pragma unroll
  for (int nf = 0; nf < 4; ++nf) acc[nf] = (floatx4){0.f, 0.f, 0.f, 0.f};
  int arow = m0 + lr;
  for (int kt = 0; kt < 8; ++kt) {
    int kb = w * 256 + kt * 32 + kg * 8;
    short8 af = *reinterpret_cast<const short8*>(&h1bf[arow * HN + kb]);
    #pragma unroll
    for (int nf = 0; nf < 4; ++nf) {
      short8 bf_ = *reinterpret_cast<const short8*>(&W2T[(n0 + nf * 16 + lr) * HN + kb]);
      acc[nf] = __builtin_amdgcn_mfma_f32_16x16x32_bf16(af, bf_, acc[nf], 0, 0, 0);
    }
  }
  #pragma unroll
  for (int nf = 0; nf < 4; ++nf)
    #pragma unroll
    for (int r = 0; r < 4; ++r)
      redL[w * 1024 + (kg * 4 + r) * 64 + nf * 16 + lr] = acc[nf][r];
  __syncthreads();
  #pragma unroll
  for (int t = 0; t < 4; ++t) {
    int e = tid + t * 256;
    float z = redL[e] + redL[1024 + e] + redL[2048 + e] + redL[3072 + e];
    int row = e >> 6, col = e & 63;
    int s = m0 + row, k2 = n0 + col;
    z += b2[k2];
    float h = tanhf(z), tt = 1.f - h * h, w3 = W3[k2];
    dcoef[s * HN + k2] = -2.f * h * tt * w3;
    vbf[s * HN + k2] = f2bf(tt * w3);
  }
}

// ---------------------------------------------------------------------------
// w = v @ W2^T  (w[s,j] = sum_k v[s,k] W2[j,k]) -> store f32
__global__ __launch_bounds__(256) void k_w(
    const unsigned short* __restrict__ vbf, const unsigned short* __restrict__ W2bf,
    float* __restrict__ wbuf) {
  __shared__ float redL[4 * 16 * 64];
  int n0 = blockIdx.x * 64, m0 = blockIdx.y * 16;
  int tid = threadIdx.x, w = tid >> 6, l = tid & 63, lr = l & 15, kg = l >> 4;
  floatx4 acc[4];
  #pragma unroll
  for (int nf = 0; nf < 4; ++nf) acc[nf] = (floatx4){0.f, 0.f, 0.f, 0.f};
  int arow = m0 + lr;
  for (int kt = 0; kt < 8; ++kt) {
    int kb = w * 256 + kt * 32 + kg * 8;
    short8 af = *reinterpret_cast<const short8*>(&vbf[arow * HN + kb]);
    #pragma unroll
    for (int nf = 0; nf < 4; ++nf) {
      short8 bf_ = *reinterpret_cast<const short8*>(&W2bf[(n0 + nf * 16 + lr) * HN + kb]);
      acc[nf] = __builtin_amdgcn_mfma_f32_16x16x32_bf16(af, bf_, acc[nf], 0, 0, 0);
    }
  }
  #pragma unroll
  for (int nf = 0; nf < 4; ++nf)
    #pragma unroll
    for (int r = 0; r < 4; ++r)
      redL[w * 1024 + (kg * 4 + r) * 64 + nf * 16 + lr] = acc[nf][r];
  __syncthreads();
  #pragma unroll
  for (int t = 0; t < 4; ++t) {
    int e = tid + t * 256;
    float z = redL[e] + redL[1024 + e] + redL[2048 + e] + redL[3072 + e];
    int row = e >> 6, col = e & 63;
    wbuf[(m0 + row) * HN + (n0 + col)] = z;
  }
}

// ---------------------------------------------------------------------------
// BIG, 8-phase schedule (T3+T4+T5), FULL batch in one launch.
// q[s,k] = sum_a M[a,k]^2, M = P[s] @ W2.  BM=256 (4 samples) x BN=256,
// BK=64 (2 k-halves of 32). 512 threads = 8 waves (2M x 4N).
// LDS: 2 dbuf x 2 khalf x 256x32 bf16 x {A,B} = 128 KB dynamic.
// Counted vmcnt(4) at phases 1,3 only; raw s_barrier; setprio around MFMA.
// LDS swizzle: 16B slot = kg ^ ((row>>1)&3); gload_lds dest linear,
// global source pre-swizzled (rule #21).
__global__ __launch_bounds__(512, 2) void k_big8(
    const unsigned short* __restrict__ Pbf,   // [32768][HN]
    const unsigned short* __restrict__ W2T, float* __restrict__ q) {
  extern __shared__ unsigned short sm[];      // [0..32767]=A, [32768..65535]=B

  // XCD-bijective swizzle: 512 blocks, 8 XCDs, 64 blocks/XCD chunk.
  // px uniform per XCD-pair -> W2T panel (512 KB) L2-resident.
  int flat = blockIdx.x;
  int virt = (flat & 7) * 64 + (flat >> 3);
  int px = virt >> 7;                          // 0..3  (col panel)
  int py = virt & 127;                         // 0..127 (4-sample chunk)

  int tid = threadIdx.x;
  int wid = tid >> 6, l = tid & 63;
  int lr = l & 15, kg = l >> 4;
  int wr = wid >> 2, wc = wid & 3;             // wave grid 2M x 4N
  int wr128 = wr * 128, wc64 = wc * 64;
  int sl8 = ((kg ^ ((lr >> 1) & 3)) << 3);     // read-side swizzled 16B slot

  int row_s = tid >> 2;
  int kgl8 = (((tid & 3) ^ ((tid >> 3) & 3)) << 3);
  const unsigned short* aSrc = &Pbf[(size_t)(py * 256 + row_s) * HN + kgl8];
  const unsigned short* bSrc = &W2T[(size_t)(px * 256 + row_s) * HN + kgl8];

  auto stA = [&](int buf, int tt, int kh) {
    const unsigned short* s = aSrc + tt * 64 + kh * 32;
    unsigned short* d = &sm[(buf * 2 + kh) * 8192] + tid * 8;
    gload_lds16(s, d);
    gload_lds16(s + 128 * HN, d + 4096);
  };
  auto stB = [&](int buf, int tt, int kh) {
    const unsigned short* s = bSrc + tt * 64 + kh * 32;
    unsigned short* d = &sm[32768 + (buf * 2 + kh) * 8192] + tid * 8;
    gload_lds16(s, d);
    gload_lds16(s + 128 * HN, d + 4096);
  };

  floatx4 acc[8][4];
  #pragma unroll
  for (int m = 0; m < 8; ++m)
    #pragma unroll
    for (int n = 0; n < 4; ++n) acc[m][n] = (floatx4){0.f, 0.f, 0.f, 0.f};

  short8 af[8], bfr[2];
  auto ldA = [&](int buf, int kh) {
    const unsigned short* Ap = &sm[(buf * 2 + kh) * 8192];
    #pragma unroll
    for (int m = 0; m < 8; ++m)
      af[m] = *reinterpret_cast<const short8*>(&Ap[(wr128 + m * 16 + lr) * 32 + sl8]);
  };
  auto ldB = [&](int buf, int kh, int nh) {
    const unsigned short* Bp = &sm[32768 + (buf * 2 + kh) * 8192];
    #pragma unroll
    for (int n = 0; n < 2; ++n)
      bfr[n] = *reinterpret_cast<const short8*>(&Bp[(wc64 + (nh * 2 + n) * 16 + lr) * 32 + sl8]);
  };
  auto mm = [&](int nh) {
    __builtin_amdgcn_s_setprio(1);
    #pragma unroll
    for (int m = 0; m < 8; ++m)
      #pragma unroll
      for (int n = 0; n < 2; ++n)
        acc[m][nh * 2 + n] =
            __builtin_amdgcn_mfma_f32_16x16x32_bf16(af[m], bfr[n], acc[m][nh * 2 + n], 0, 0, 0);
    __builtin_amdgcn_s_setprio(0);
  };

  // prologue: stage all 4 halves of tile 0; wait first 2 (Ak0,Bk0)
  stA(0, 0, 0); stB(0, 0, 0); stA(0, 0, 1); stB(0, 0, 1);
  WAITV4; PH_BAR;

  for (int t = 0; t < 16; ++t) {
    int buf = t & 1, nb = buf ^ 1;
    bool more = (t < 15);
    // ph0: (k0, nh0)
    ldA(buf, 0); ldB(buf, 0, 0);
    if (more) stA(nb, t + 1, 0);
    PH_BAR; mm(0); PH_BAR;
    // ph1: (k0, nh1); guard k1 halves
    ldB(buf, 0, 1);
    if (more) { stB(nb, t + 1, 0); WAITV4; } else { WAITV0; }
    PH_BAR; mm(1); PH_BAR;
    // ph2: (k1, nh0)
    ldA(buf, 1); ldB(buf, 1, 0);
    if (more) stA(nb, t + 1, 1);
    PH_BAR; mm(0); PH_BAR;
    // ph3: (k1, nh1); guard next tile's k0 halves
    ldB(buf, 1, 1);
    if (more) { stB(nb, t + 1, 1); WAITV4; }
    PH_BAR; mm(1); PH_BAR;
  }

  // epilogue: per wave 2 samples x 64 cols; reduce rows of M^2
  int colBase = px * 256 + wc64;
  #pragma unroll
  for (int half = 0; half < 2; ++half) {
    int sOut = py * 4 + wr * 2 + half;
    #pragma unroll
    for (int nf = 0; nf < 4; ++nf) {
      float v = 0.f;
      #pragma unroll
      for (int mf = half * 4; mf < half * 4 + 4; ++mf)
        #pragma unroll
        for (int r = 0; r < 4; ++r) v += acc[mf][nf][r] * acc[mf][nf][r];
      v += __shfl_xor(v, 16, 64);
      v += __shfl_xor(v, 32, 64);
      if (l < 16) q[(size_t)sOut * HN + colBase + nf * 16 + l] = v;
    }
  }
}

// ---------------------------------------------------------------------------
// finale: per sample combine T1, T2, sum g^2, pot+gint
__global__ __launch_bounds__(256) void k_fin(
    const float* __restrict__ wbuf, const float* __restrict__ a1,
    const float* __restrict__ dcoef, const float* __restrict__ q,
    const float* __restrict__ t1f, const float* __restrict__ W1T,
    const float* __restrict__ potgint, float* __restrict__ out) {
  __shared__ float s_lds[HN];
  __shared__ float gl[256];
  __shared__ float red1[4], red2[4];
  int s = blockIdx.x, tid = threadIdx.x;
  float p1 = 0.f, p2 = 0.f;
  #pragma unroll
  for (int cc = 0; cc < 4; ++cc) {
    int j = tid + cc * 256;
    float wv = wbuf[s * HN + j];
    p1 += a1[s * HN + j] * wv;
    p2 += dcoef[s * HN + j] * q[s * HN + j];
    s_lds[j] = t1f[s * HN + j] * wv;
  }
  __syncthreads();
  int part = tid >> 6, a = tid & 63;
  float gp = 0.f;
  for (int jj = part * 256; jj < part * 256 + 256; ++jj)
    gp += s_lds[jj] * W1T[jj * AN + a];
  gl[tid] = gp;
  #pragma unroll
  for (int o = 32; o > 0; o >>= 1) { p1 += __shfl_down(p1, o, 64); p2 += __shfl_down(p2, o, 64); }
  if ((tid & 63) == 0) { red1[tid >> 6] = p1; red2[tid >> 6] = p2; }
  __syncthreads();
  if (tid < 64) {
    float g = gl[tid] + gl[64 + tid] + gl[128 + tid] + gl[192 + tid];
    float sq = g * g;
    #pragma unroll
    for (int o = 32; o > 0; o >>= 1) sq += __shfl_down(sq, o, 64);
    if (tid == 0) {
      float T1 = -2.f * (red1[0] + red1[1] + red1[2] + red1[3]);
      float T2 = red2[0] + red2[1] + red2[2] + red2[3];
      out[s] = -0.5f * (T1 + T2 + sq) + potgint[s];
    }
  }
}

// ---------------------------------------------------------------------------
extern "C" void kernel_launch(void* const* d_in, const int* in_sizes, int n_in,
                              void* d_out, int out_size, void* d_ws, size_t ws_size,
                              hipStream_t stream) {
  const float* x  = (const float*)d_in[0];
  const float* W1 = (const float*)d_in[1];
  const float* b1 = (const float*)d_in[2];
  const float* W2 = (const float*)d_in[3];
  const float* b2 = (const float*)d_in[4];
  const float* W3 = (const float*)d_in[5];
  float* out = (float*)d_out;

  char* ws = (char*)d_ws;
  size_t off = 0;
  auto alloc = [&](size_t bytes) -> void* {
    void* p = ws + off; off += (bytes + 255) & ~(size_t)255; return p;
  };
  unsigned short* W2T  = (unsigned short*)alloc((size_t)HN * HN * 2);
  unsigned short* W2bf = (unsigned short*)alloc((size_t)HN * HN * 2);
  float*          W1T  = (float*)alloc((size_t)AN * HN * 4);
  unsigned short* h1bf = (unsigned short*)alloc((size_t)BN * HN * 2);
  float*          t1f  = (float*)alloc((size_t)BN * HN * 4);
  float*          a1   = (float*)alloc((size_t)BN * HN * 4);
  float*          dcoef= (float*)alloc((size_t)BN * HN * 4);
  unsigned short* vbf  = (unsigned short*)alloc((size_t)BN * HN * 2);
  float*          wbuf = (float*)alloc((size_t)BN * HN * 4);
  float*          q    = (float*)alloc((size_t)BN * HN * 4);
  float*          pg   = (float*)alloc((size_t)BN * 4);
  // full-batch P buffer: 512 samples x 64 x 1024 bf16 = 67 MB
  unsigned short* Pbf  = (unsigned short*)alloc((size_t)BN * AN * HN * 2);

  static bool attrSet = false;
  if (!attrSet) {
    hipFuncSetAttribute((const void*)k_big8,
                        hipFuncAttributeMaxDynamicSharedMemorySize, 131072);
    attrSet = true;
  }

  k_fwd1<<<dim3(BN), 256, 0, stream>>>(x, W1, b1, h1bf, t1f, a1, pg);
  k_packprep<<<dim3(16384 + 256 + 16), 256, 0, stream>>>(W1, t1f, W2,
                                                         Pbf, W2T, W2bf, W1T);
  k_z2<<<dim3(HN / 64, BN / 16), 256, 0, stream>>>(h1bf, W2T, b2, W3, dcoef, vbf);
  k_w<<<dim3(HN / 64, BN / 16), 256, 0, stream>>>(vbf, W2bf, wbuf);
  k_big8<<<dim3(512), 512, 131072, stream>>>(Pbf, W2T, q);
  k_fin<<<dim3(BN), 256, 0, stream>>>(wbuf, a1, dcoef, q, t1f, W1T, pg, out);
}